// Round 1
// baseline (7603.123 us; speedup 1.0000x reference)
//
#include <hip/hip_runtime.h>

#define HD 64

__device__ __forceinline__ float elu_f(float x) { return x > 0.0f ? x : __expf(x) - 1.0f; }

// ---------------- encoders: h = elu(x @ W + b), x:[N,FIN], W:[FIN,64] ----------------
template<int FIN>
__global__ void encode_kernel(const float* __restrict__ x, const float* __restrict__ W,
                              const float* __restrict__ b, float* __restrict__ h, int N) {
    __shared__ float sW[FIN * HD];
    int t = threadIdx.x;
    for (int i = t; i < FIN * HD; i += 256) sW[i] = W[i];
    __syncthreads();
    int r = blockIdx.x * 4 + (t >> 6);
    int c = t & 63;
    if (r >= N) return;
    float acc = b[c];
#pragma unroll
    for (int k = 0; k < FIN; ++k) acc = fmaf(x[r * FIN + k], sW[k * HD + c], acc);
    h[r * HD + c] = elu_f(acc);
}

// ---------------- degree count + reciprocal ----------------
__global__ void count_deg_kernel(const int* __restrict__ dst, float* __restrict__ deg, int E) {
    int i = blockIdx.x * blockDim.x + threadIdx.x;
    if (i < E) atomicAdd(&deg[dst[i]], 1.0f);
}

__global__ void rdeg_kernel(float* __restrict__ deg, int n) {
    int i = blockIdx.x * blockDim.x + threadIdx.x;
    if (i < n) deg[i] = 1.0f / fmaxf(deg[i], 1.0f);
}

// ---------------- scatter-add: agg[dst[e]] += h_src[src[e]]  (16 thr/edge, float4) ----
__global__ void scatter_kernel(const float* __restrict__ hsrc, const int* __restrict__ src,
                               const int* __restrict__ dst, float* __restrict__ agg, int E) {
    int t = blockIdx.x * blockDim.x + threadIdx.x;
    int e = t >> 4, q = t & 15;
    if (e >= E) return;
    int s = src[e], d = dst[e];
    const float4 v = *reinterpret_cast<const float4*>(hsrc + (size_t)s * HD + q * 4);
    float* a = agg + (size_t)d * HD + q * 4;
    atomicAdd(a + 0, v.x);
    atomicAdd(a + 1, v.y);
    atomicAdd(a + 2, v.z);
    atomicAdd(a + 3, v.w);
}

// ---------------- SAGE out: hn += (agg*rdeg) @ Wl + bl + h_dst @ Wr ----------------
__global__ void sage_out_kernel(const float* __restrict__ agg, const float* __restrict__ rdeg,
                                const float* __restrict__ hdst,
                                const float* __restrict__ Wl, const float* __restrict__ bl,
                                const float* __restrict__ Wr,
                                float* __restrict__ hn, int N) {
    __shared__ float sWl[HD * HD];
    __shared__ float sWr[HD * HD];
    int t = threadIdx.x;
    for (int i = t; i < HD * HD; i += 256) { sWl[i] = Wl[i]; sWr[i] = Wr[i]; }
    __syncthreads();
    int r = blockIdx.x * 4 + (t >> 6);
    int c = t & 63;
    if (r >= N) return;
    const float* ar = agg + (size_t)r * HD;
    const float* hr = hdst + (size_t)r * HD;
    float acca = 0.0f, acch = 0.0f;
#pragma unroll 8
    for (int k = 0; k < HD; ++k) {
        acca = fmaf(ar[k], sWl[k * HD + c], acca);
        acch = fmaf(hr[k], sWr[k * HD + c], acch);
    }
    hn[(size_t)r * HD + c] += acca * rdeg[r] + bl[c] + acch;
}

// ---------------- residual + LayerNorm + ELU (one wave per row) ----------------
__global__ void ln_elu_kernel(float* __restrict__ h, const float* __restrict__ hn,
                              const float* __restrict__ g, const float* __restrict__ b, int N) {
    int t = threadIdx.x;
    int r = blockIdx.x * 4 + (t >> 6);
    int c = t & 63;
    if (r >= N) return;
    float v = h[(size_t)r * HD + c] + hn[(size_t)r * HD + c];
    float s = v;
#pragma unroll
    for (int o = 32; o > 0; o >>= 1) s += __shfl_xor(s, o, 64);
    float mean = s * (1.0f / 64.0f);
    float d = v - mean;
    float sq = d * d;
#pragma unroll
    for (int o = 32; o > 0; o >>= 1) sq += __shfl_xor(sq, o, 64);
    float var = sq * (1.0f / 64.0f);
    float y = d * rsqrtf(var + 1e-5f) * g[c] + b[c];
    h[(size_t)r * HD + c] = elu_f(y);
}

// ---------------- cox head: out = elu(h @ W1 + b1) @ W2 + b2 ----------------
__global__ void cox_kernel(const float* __restrict__ hp,
                           const float* __restrict__ W1, const float* __restrict__ b1,
                           const float* __restrict__ W2, const float* __restrict__ b2,
                           float* __restrict__ out, int N) {
    __shared__ float sW1[HD * 32];
    __shared__ float sW2[32];
    int t = threadIdx.x;
    for (int i = t; i < HD * 32; i += 256) sW1[i] = W1[i];
    if (t < 32) sW2[t] = W2[t];
    __syncthreads();
    int r = blockIdx.x * 8 + (t >> 5);
    int c = t & 31;
    if (r >= N) return;
    const float* hr = hp + (size_t)r * HD;
    float acc = b1[c];
#pragma unroll 8
    for (int k = 0; k < HD; ++k) acc = fmaf(hr[k], sW1[k * 32 + c], acc);
    float z = elu_f(acc) * sW2[c];
#pragma unroll
    for (int o = 16; o > 0; o >>= 1) z += __shfl_xor(z, o, 32);
    if (c == 0) out[r] = z + b2[0];
}

extern "C" void kernel_launch(void* const* d_in, const int* in_sizes, int n_in,
                              void* d_out, int out_size, void* d_ws, size_t ws_size,
                              hipStream_t stream) {
    const float* x_gene    = (const float*)d_in[0];
    const float* x_patient = (const float*)d_in[1];
    const float* x_group   = (const float*)d_in[2];
    const int* srcs[4] = {(const int*)d_in[3], (const int*)d_in[5], (const int*)d_in[7], (const int*)d_in[9]};
    const int* dsts[4] = {(const int*)d_in[4], (const int*)d_in[6], (const int*)d_in[8], (const int*)d_in[10]};
    const float* enc_gene_W    = (const float*)d_in[11];
    const float* enc_gene_b    = (const float*)d_in[12];
    const float* enc_patient_W = (const float*)d_in[13];
    const float* enc_patient_b = (const float*)d_in[14];
    const float* enc_group_W   = (const float*)d_in[15];
    const float* enc_group_b   = (const float*)d_in[16];
    const float* convW_l = (const float*)d_in[17];  // [2,4,64,64]
    const float* convb_l = (const float*)d_in[18];  // [2,4,64]
    const float* convW_r = (const float*)d_in[19];  // [2,4,64,64]
    const float* ln_gamma = (const float*)d_in[20]; // [2,3,64]
    const float* ln_beta  = (const float*)d_in[21];
    const float* coxW1 = (const float*)d_in[22];
    const float* coxb1 = (const float*)d_in[23];
    const float* coxW2 = (const float*)d_in[24];
    const float* coxb2 = (const float*)d_in[25];
    float* out = (float*)d_out;

    const int n_gene    = in_sizes[0] / 11;
    const int n_patient = in_sizes[1] / 3;
    const int n_group   = in_sizes[2] / 4;
    const int E         = in_sizes[3];

    // ---- workspace layout (floats) ----
    float* ws = (float*)d_ws;
    float* h_gene  = ws;                          ws += (size_t)n_gene * HD;
    float* h_pat   = ws;                          ws += (size_t)n_patient * HD;
    float* h_grp   = ws;                          ws += (size_t)n_group * HD;
    float* hn_base = ws;                          // hn_gene, hn_pat, hn_grp contiguous
    float* hn_gene = ws;                          ws += (size_t)n_gene * HD;
    float* hn_pat  = ws;                          ws += (size_t)n_patient * HD;
    float* hn_grp  = ws;                          ws += (size_t)n_group * HD;
    float* agg     = ws;                          ws += (size_t)n_patient * HD; // max dst count
    float* deg_base = ws;                         // rdeg0..3 contiguous
    float* rdeg[4];
    rdeg[0] = ws; ws += n_patient;
    rdeg[1] = ws; ws += n_gene;
    rdeg[2] = ws; ws += n_group;
    rdeg[3] = ws; ws += n_gene;

    const size_t hn_total   = ((size_t)n_gene + n_patient + n_group) * HD;
    const int    deg_total  = n_patient + n_gene + n_group + n_gene;

    // edge-type tables: src h, dst h(root), dst hn, dst count
    const float* e_hsrc[4] = {h_gene, h_pat, h_gene, h_grp};
    const float* e_hdst[4] = {h_pat, h_gene, h_grp, h_gene};
    float*       e_hn[4]   = {hn_pat, hn_gene, hn_grp, hn_gene};
    const int    e_nd[4]   = {n_patient, n_gene, n_group, n_gene};
    // node-type tables (NODE_ORDER = gene, patient, mutation_group)
    float*    nt_h[3]  = {h_gene, h_pat, h_grp};
    float*    nt_hn[3] = {hn_gene, hn_pat, hn_grp};
    const int nt_n[3]  = {n_gene, n_patient, n_group};

    // ---- encoders ----
    encode_kernel<11><<<(n_gene + 3) / 4, 256, 0, stream>>>(x_gene, enc_gene_W, enc_gene_b, h_gene, n_gene);
    encode_kernel<3><<<(n_patient + 3) / 4, 256, 0, stream>>>(x_patient, enc_patient_W, enc_patient_b, h_pat, n_patient);
    encode_kernel<4><<<(n_group + 3) / 4, 256, 0, stream>>>(x_group, enc_group_W, enc_group_b, h_grp, n_group);

    // ---- reciprocal degrees (layer-invariant) ----
    hipMemsetAsync(deg_base, 0, (size_t)deg_total * sizeof(float), stream);
    for (int e = 0; e < 4; ++e)
        count_deg_kernel<<<(E + 255) / 256, 256, 0, stream>>>(dsts[e], rdeg[e], E);
    rdeg_kernel<<<(deg_total + 255) / 256, 256, 0, stream>>>(deg_base, deg_total);

    // ---- 2 GNN layers ----
    for (int layer = 0; layer < 2; ++layer) {
        hipMemsetAsync(hn_base, 0, hn_total * sizeof(float), stream);
        for (int e = 0; e < 4; ++e) {
            const int nd = e_nd[e];
            hipMemsetAsync(agg, 0, (size_t)nd * HD * sizeof(float), stream);
            scatter_kernel<<<((size_t)E * 16 + 255) / 256, 256, 0, stream>>>(
                e_hsrc[e], srcs[e], dsts[e], agg, E);
            const int pe = layer * 4 + e;
            sage_out_kernel<<<(nd + 3) / 4, 256, 0, stream>>>(
                agg, rdeg[e], e_hdst[e],
                convW_l + (size_t)pe * HD * HD, convb_l + (size_t)pe * HD,
                convW_r + (size_t)pe * HD * HD, e_hn[e], nd);
        }
        for (int ni = 0; ni < 3; ++ni) {
            const int pn = layer * 3 + ni;
            ln_elu_kernel<<<(nt_n[ni] + 3) / 4, 256, 0, stream>>>(
                nt_h[ni], nt_hn[ni], ln_gamma + (size_t)pn * HD, ln_beta + (size_t)pn * HD, nt_n[ni]);
        }
    }

    // ---- cox head ----
    cox_kernel<<<(n_patient + 7) / 8, 256, 0, stream>>>(h_pat, coxW1, coxb1, coxW2, coxb2, out, n_patient);
}

// Round 2
// 1472.201 us; speedup vs baseline: 5.1645x; 5.1645x over previous
//
#include <hip/hip_runtime.h>

#define HD 64

__device__ __forceinline__ float elu_f(float x) { return x > 0.0f ? x : __expf(x) - 1.0f; }

// ---------------- encoders: h = elu(x @ W + b), x:[N,FIN], W:[FIN,64] ----------------
template<int FIN>
__global__ void encode_kernel(const float* __restrict__ x, const float* __restrict__ W,
                              const float* __restrict__ b, float* __restrict__ h, int N) {
    __shared__ float sW[FIN * HD];
    int t = threadIdx.x;
    for (int i = t; i < FIN * HD; i += 256) sW[i] = W[i];
    __syncthreads();
    int r = blockIdx.x * 4 + (t >> 6);
    int c = t & 63;
    if (r >= N) return;
    float acc = b[c];
#pragma unroll
    for (int k = 0; k < FIN; ++k) acc = fmaf(x[r * FIN + k], sW[k * HD + c], acc);
    h[r * HD + c] = elu_f(acc);
}

// ---------------- CSR build ----------------
__global__ void count_deg_kernel(const int* __restrict__ dst, int* __restrict__ cnt, int E) {
    int i = blockIdx.x * blockDim.x + threadIdx.x;
    if (i < E) atomicAdd(&cnt[dst[i]], 1);
}

// rdeg = 1/max(cnt,1) over the concatenated count arrays
__global__ void rdeg_kernel(const int* __restrict__ cnt, float* __restrict__ rdeg, int n) {
    int i = blockIdx.x * blockDim.x + threadIdx.x;
    if (i < n) rdeg[i] = 1.0f / fmaxf((float)cnt[i], 1.0f);
}

// single-block exclusive scan (n <= ~1M): 1024 threads, serial chunk + LDS scan
__global__ __launch_bounds__(1024) void exscan_kernel(const int* __restrict__ cnt,
                                                      int* __restrict__ off, int n) {
    __shared__ int s[1024];
    int t = threadIdx.x;
    int chunk = (n + 1023) / 1024;
    int lo = t * chunk, hi = min(lo + chunk, n);
    int sum = 0;
    for (int i = lo; i < hi; ++i) sum += cnt[i];
    s[t] = sum;
    __syncthreads();
    // inclusive Hillis-Steele scan over s
    for (int ofs = 1; ofs < 1024; ofs <<= 1) {
        int v = (t >= ofs) ? s[t - ofs] : 0;
        __syncthreads();
        s[t] += v;
        __syncthreads();
    }
    int run = (t == 0) ? 0 : s[t - 1];
    for (int i = lo; i < hi; ++i) { off[i] = run; run += cnt[i]; }
    if (t == 1023) off[n] = s[1023];
}

// place src ids into dst buckets: ssorted[off[d] + pos] = src
__global__ void place_kernel(const int* __restrict__ src, const int* __restrict__ dst,
                             const int* __restrict__ off, int* __restrict__ cursor,
                             int* __restrict__ ssorted, int E) {
    int i = blockIdx.x * blockDim.x + threadIdx.x;
    if (i >= E) return;
    int d = dst[i];
    int p = atomicAdd(&cursor[d], 1);
    ssorted[off[d] + p] = src[i];
}

// ---------------- gather-mean: agg[d] = mean_{s in N(d)} hsrc[s] (16 lanes/node) ----
__global__ void gather_agg_kernel(const float* __restrict__ hsrc, const int* __restrict__ off,
                                  const int* __restrict__ ssorted, const float* __restrict__ rdeg,
                                  float* __restrict__ agg, int N) {
    int t = blockIdx.x * blockDim.x + threadIdx.x;
    int d = t >> 4, q = t & 15;
    if (d >= N) return;
    int lo = off[d], hi = off[d + 1];
    float a0x = 0, a0y = 0, a0z = 0, a0w = 0;
    float a1x = 0, a1y = 0, a1z = 0, a1w = 0;
    int j = lo;
    for (; j + 2 <= hi; j += 2) {
        int s0 = ssorted[j], s1 = ssorted[j + 1];
        const float4 v0 = *reinterpret_cast<const float4*>(hsrc + (size_t)s0 * HD + q * 4);
        const float4 v1 = *reinterpret_cast<const float4*>(hsrc + (size_t)s1 * HD + q * 4);
        a0x += v0.x; a0y += v0.y; a0z += v0.z; a0w += v0.w;
        a1x += v1.x; a1y += v1.y; a1z += v1.z; a1w += v1.w;
    }
    if (j < hi) {
        int s0 = ssorted[j];
        const float4 v0 = *reinterpret_cast<const float4*>(hsrc + (size_t)s0 * HD + q * 4);
        a0x += v0.x; a0y += v0.y; a0z += v0.z; a0w += v0.w;
    }
    float r = rdeg[d];
    float4 o;
    o.x = (a0x + a1x) * r; o.y = (a0y + a1y) * r; o.z = (a0z + a1z) * r; o.w = (a0w + a1w) * r;
    *reinterpret_cast<float4*>(agg + (size_t)d * HD + q * 4) = o;
}

// ---------------- SAGE out: hn += agg @ Wl + bl + h_dst @ Wr ----------------
__global__ void sage_out_kernel(const float* __restrict__ agg,
                                const float* __restrict__ hdst,
                                const float* __restrict__ Wl, const float* __restrict__ bl,
                                const float* __restrict__ Wr,
                                float* __restrict__ hn, int N) {
    __shared__ float sWl[HD * HD];
    __shared__ float sWr[HD * HD];
    int t = threadIdx.x;
    for (int i = t; i < HD * HD; i += 256) { sWl[i] = Wl[i]; sWr[i] = Wr[i]; }
    __syncthreads();
    int r = blockIdx.x * 4 + (t >> 6);
    int c = t & 63;
    if (r >= N) return;
    const float* ar = agg + (size_t)r * HD;
    const float* hr = hdst + (size_t)r * HD;
    float acca = 0.0f, acch = 0.0f;
#pragma unroll 8
    for (int k = 0; k < HD; ++k) {
        acca = fmaf(ar[k], sWl[k * HD + c], acca);
        acch = fmaf(hr[k], sWr[k * HD + c], acch);
    }
    hn[(size_t)r * HD + c] += acca + bl[c] + acch;
}

// ---------------- residual + LayerNorm + ELU (one wave per row) ----------------
__global__ void ln_elu_kernel(float* __restrict__ h, const float* __restrict__ hn,
                              const float* __restrict__ g, const float* __restrict__ b, int N) {
    int t = threadIdx.x;
    int r = blockIdx.x * 4 + (t >> 6);
    int c = t & 63;
    if (r >= N) return;
    float v = h[(size_t)r * HD + c] + hn[(size_t)r * HD + c];
    float s = v;
#pragma unroll
    for (int o = 32; o > 0; o >>= 1) s += __shfl_xor(s, o, 64);
    float mean = s * (1.0f / 64.0f);
    float d = v - mean;
    float sq = d * d;
#pragma unroll
    for (int o = 32; o > 0; o >>= 1) sq += __shfl_xor(sq, o, 64);
    float var = sq * (1.0f / 64.0f);
    float y = d * rsqrtf(var + 1e-5f) * g[c] + b[c];
    h[(size_t)r * HD + c] = elu_f(y);
}

// ---------------- cox head: out = elu(h @ W1 + b1) @ W2 + b2 ----------------
__global__ void cox_kernel(const float* __restrict__ hp,
                           const float* __restrict__ W1, const float* __restrict__ b1,
                           const float* __restrict__ W2, const float* __restrict__ b2,
                           float* __restrict__ out, int N) {
    __shared__ float sW1[HD * 32];
    __shared__ float sW2[32];
    int t = threadIdx.x;
    for (int i = t; i < HD * 32; i += 256) sW1[i] = W1[i];
    if (t < 32) sW2[t] = W2[t];
    __syncthreads();
    int r = blockIdx.x * 8 + (t >> 5);
    int c = t & 31;
    if (r >= N) return;
    const float* hr = hp + (size_t)r * HD;
    float acc = b1[c];
#pragma unroll 8
    for (int k = 0; k < HD; ++k) acc = fmaf(hr[k], sW1[k * 32 + c], acc);
    float z = elu_f(acc) * sW2[c];
#pragma unroll
    for (int o = 16; o > 0; o >>= 1) z += __shfl_xor(z, o, 32);
    if (c == 0) out[r] = z + b2[0];
}

extern "C" void kernel_launch(void* const* d_in, const int* in_sizes, int n_in,
                              void* d_out, int out_size, void* d_ws, size_t ws_size,
                              hipStream_t stream) {
    const float* x_gene    = (const float*)d_in[0];
    const float* x_patient = (const float*)d_in[1];
    const float* x_group   = (const float*)d_in[2];
    const int* srcs[4] = {(const int*)d_in[3], (const int*)d_in[5], (const int*)d_in[7], (const int*)d_in[9]};
    const int* dsts[4] = {(const int*)d_in[4], (const int*)d_in[6], (const int*)d_in[8], (const int*)d_in[10]};
    const float* enc_gene_W    = (const float*)d_in[11];
    const float* enc_gene_b    = (const float*)d_in[12];
    const float* enc_patient_W = (const float*)d_in[13];
    const float* enc_patient_b = (const float*)d_in[14];
    const float* enc_group_W   = (const float*)d_in[15];
    const float* enc_group_b   = (const float*)d_in[16];
    const float* convW_l = (const float*)d_in[17];  // [2,4,64,64]
    const float* convb_l = (const float*)d_in[18];  // [2,4,64]
    const float* convW_r = (const float*)d_in[19];  // [2,4,64,64]
    const float* ln_gamma = (const float*)d_in[20]; // [2,3,64]
    const float* ln_beta  = (const float*)d_in[21];
    const float* coxW1 = (const float*)d_in[22];
    const float* coxb1 = (const float*)d_in[23];
    const float* coxW2 = (const float*)d_in[24];
    const float* coxb2 = (const float*)d_in[25];
    float* out = (float*)d_out;

    const int n_gene    = in_sizes[0] / 11;
    const int n_patient = in_sizes[1] / 3;
    const int n_group   = in_sizes[2] / 4;
    const int E         = in_sizes[3];

    // ---- workspace layout ----
    float* wf = (float*)d_ws;
    float* h_gene  = wf;                          wf += (size_t)n_gene * HD;
    float* h_pat   = wf;                          wf += (size_t)n_patient * HD;
    float* h_grp   = wf;                          wf += (size_t)n_group * HD;
    float* hn_base = wf;
    float* hn_gene = wf;                          wf += (size_t)n_gene * HD;
    float* hn_pat  = wf;                          wf += (size_t)n_patient * HD;
    float* hn_grp  = wf;                          wf += (size_t)n_group * HD;
    float* agg     = wf;                          wf += (size_t)n_patient * HD; // max dst count
    float* rdeg_base = wf;                        // concatenated, same order as cnt_base
    float* rdeg[4];
    rdeg[0] = wf; wf += n_patient;
    rdeg[1] = wf; wf += n_gene;
    rdeg[2] = wf; wf += n_group;
    rdeg[3] = wf; wf += n_gene;

    int* wi = (int*)wf;
    int* cnt_base = wi;                           // concatenated counts / cursors
    int* cnt[4];
    cnt[0] = wi; wi += n_patient;
    cnt[1] = wi; wi += n_gene;
    cnt[2] = wi; wi += n_group;
    cnt[3] = wi; wi += n_gene;
    int* off[4];
    off[0] = wi; wi += n_patient + 1;
    off[1] = wi; wi += n_gene + 1;
    off[2] = wi; wi += n_group + 1;
    off[3] = wi; wi += n_gene + 1;
    int* ssorted[4];
    ssorted[0] = wi; wi += E;
    ssorted[1] = wi; wi += E;
    ssorted[2] = wi; wi += E;
    ssorted[3] = wi; wi += E;

    const size_t hn_total  = ((size_t)n_gene + n_patient + n_group) * HD;
    const int    deg_total = n_patient + n_gene + n_group + n_gene;

    const float* e_hsrc[4] = {h_gene, h_pat, h_gene, h_grp};
    const float* e_hdst[4] = {h_pat, h_gene, h_grp, h_gene};
    float*       e_hn[4]   = {hn_pat, hn_gene, hn_grp, hn_gene};
    const int    e_nd[4]   = {n_patient, n_gene, n_group, n_gene};
    float*    nt_h[3]  = {h_gene, h_pat, h_grp};
    float*    nt_hn[3] = {hn_gene, hn_pat, hn_grp};
    const int nt_n[3]  = {n_gene, n_patient, n_group};

    // ---- encoders ----
    encode_kernel<11><<<(n_gene + 3) / 4, 256, 0, stream>>>(x_gene, enc_gene_W, enc_gene_b, h_gene, n_gene);
    encode_kernel<3><<<(n_patient + 3) / 4, 256, 0, stream>>>(x_patient, enc_patient_W, enc_patient_b, h_pat, n_patient);
    encode_kernel<4><<<(n_group + 3) / 4, 256, 0, stream>>>(x_group, enc_group_W, enc_group_b, h_grp, n_group);

    // ---- CSR build (layer-invariant, built once) ----
    hipMemsetAsync(cnt_base, 0, (size_t)deg_total * sizeof(int), stream);
    for (int e = 0; e < 4; ++e)
        count_deg_kernel<<<(E + 255) / 256, 256, 0, stream>>>(dsts[e], cnt[e], E);
    rdeg_kernel<<<(deg_total + 255) / 256, 256, 0, stream>>>(cnt_base, rdeg_base, deg_total);
    for (int e = 0; e < 4; ++e)
        exscan_kernel<<<1, 1024, 0, stream>>>(cnt[e], off[e], e_nd[e]);
    hipMemsetAsync(cnt_base, 0, (size_t)deg_total * sizeof(int), stream);  // reuse as cursors
    for (int e = 0; e < 4; ++e)
        place_kernel<<<(E + 255) / 256, 256, 0, stream>>>(srcs[e], dsts[e], off[e], cnt[e], ssorted[e], E);

    // ---- 2 GNN layers ----
    for (int layer = 0; layer < 2; ++layer) {
        hipMemsetAsync(hn_base, 0, hn_total * sizeof(float), stream);
        for (int e = 0; e < 4; ++e) {
            const int nd = e_nd[e];
            gather_agg_kernel<<<((size_t)nd * 16 + 255) / 256, 256, 0, stream>>>(
                e_hsrc[e], off[e], ssorted[e], rdeg[e], agg, nd);
            const int pe = layer * 4 + e;
            sage_out_kernel<<<(nd + 3) / 4, 256, 0, stream>>>(
                agg, e_hdst[e],
                convW_l + (size_t)pe * HD * HD, convb_l + (size_t)pe * HD,
                convW_r + (size_t)pe * HD * HD, e_hn[e], nd);
        }
        for (int ni = 0; ni < 3; ++ni) {
            const int pn = layer * 3 + ni;
            ln_elu_kernel<<<(nt_n[ni] + 3) / 4, 256, 0, stream>>>(
                nt_h[ni], nt_hn[ni], ln_gamma + (size_t)pn * HD, ln_beta + (size_t)pn * HD, nt_n[ni]);
        }
    }

    // ---- cox head ----
    cox_kernel<<<(n_patient + 7) / 8, 256, 0, stream>>>(h_pat, coxW1, coxb1, coxW2, coxb2, out, n_patient);
}

// Round 3
// 1330.322 us; speedup vs baseline: 5.7152x; 1.1066x over previous
//
#include <hip/hip_runtime.h>

#define HD 64

__device__ __forceinline__ float elu_f(float x) { return x > 0.0f ? x : __expf(x) - 1.0f; }

// ---------------- encoders: h = elu(x @ W + b), x:[N,FIN], W:[FIN,64] ----------------
template<int FIN>
__global__ void encode_kernel(const float* __restrict__ x, const float* __restrict__ W,
                              const float* __restrict__ b, float* __restrict__ h, int N) {
    __shared__ float sW[FIN * HD];
    int t = threadIdx.x;
    for (int i = t; i < FIN * HD; i += 256) sW[i] = W[i];
    __syncthreads();
    int r = blockIdx.x * 4 + (t >> 6);
    int c = t & 63;
    if (r >= N) return;
    float acc = b[c];
#pragma unroll
    for (int k = 0; k < FIN; ++k) acc = fmaf(x[r * FIN + k], sW[k * HD + c], acc);
    h[r * HD + c] = elu_f(acc);
}

// ---------------- degree histogram, 4 edge types in one dispatch (gridDim.y = e) ----
__global__ void count_deg4_kernel(const int* __restrict__ d0, const int* __restrict__ d1,
                                  const int* __restrict__ d2, const int* __restrict__ d3,
                                  int* c0, int* c1, int* c2, int* c3, int E) {
    int i = blockIdx.x * blockDim.x + threadIdx.x;
    if (i >= E) return;
    int e = blockIdx.y;
    const int* d = (e == 0) ? d0 : (e == 1) ? d1 : (e == 2) ? d2 : d3;
    int* c = (e == 0) ? c0 : (e == 1) ? c1 : (e == 2) ? c2 : c3;
    atomicAdd(&c[d[i]], 1);
}

__global__ void rdeg_kernel(const int* __restrict__ cnt, float* __restrict__ rdeg, int n) {
    int i = blockIdx.x * blockDim.x + threadIdx.x;
    if (i < n) rdeg[i] = 1.0f / fmaxf((float)cnt[i], 1.0f);
}

// ---------------- multi-block exclusive scan over concatenated counts ----------------
#define SCAN_TPB 256
#define SCAN_EPT 8
#define SCAN_EPB (SCAN_TPB * SCAN_EPT)  // 2048

__global__ void scan_block_sum(const int* __restrict__ cnt, int* __restrict__ bsum, int n) {
    int base = blockIdx.x * SCAN_EPB;
    int t = threadIdx.x;
    int sum = 0;
    for (int i = t; i < SCAN_EPB; i += SCAN_TPB) {
        int idx = base + i;
        if (idx < n) sum += cnt[idx];
    }
    __shared__ int s[SCAN_TPB];
    s[t] = sum;
    __syncthreads();
    for (int ofs = SCAN_TPB / 2; ofs > 0; ofs >>= 1) {
        if (t < ofs) s[t] += s[t + ofs];
        __syncthreads();
    }
    if (t == 0) bsum[blockIdx.x] = s[0];
}

__global__ __launch_bounds__(1024) void scan_bsum_kernel(int* bsum, int nb) {
    __shared__ int s[1024];
    int t = threadIdx.x;
    s[t] = (t < nb) ? bsum[t] : 0;
    __syncthreads();
    for (int ofs = 1; ofs < 1024; ofs <<= 1) {
        int v = (t >= ofs) ? s[t - ofs] : 0;
        __syncthreads();
        s[t] += v;
        __syncthreads();
    }
    if (t < nb) bsum[t] = (t == 0) ? 0 : s[t - 1];
}

__global__ void scan_write_kernel(const int* __restrict__ cnt, const int* __restrict__ bsum,
                                  int* __restrict__ off, int n) {
    int base = blockIdx.x * SCAN_EPB;
    int t = threadIdx.x;
    int lo = base + t * SCAN_EPT;
    int vals[SCAN_EPT];
    int sum = 0;
#pragma unroll
    for (int i = 0; i < SCAN_EPT; ++i) {
        int idx = lo + i;
        vals[i] = (idx < n) ? cnt[idx] : 0;
        sum += vals[i];
    }
    __shared__ int s[SCAN_TPB];
    s[t] = sum;
    __syncthreads();
    for (int ofs = 1; ofs < SCAN_TPB; ofs <<= 1) {
        int v = (t >= ofs) ? s[t - ofs] : 0;
        __syncthreads();
        s[t] += v;
        __syncthreads();
    }
    int run = bsum[blockIdx.x] + ((t == 0) ? 0 : s[t - 1]);
#pragma unroll
    for (int i = 0; i < SCAN_EPT; ++i) {
        int idx = lo + i;
        if (idx < n) off[idx] = run;
        run += vals[i];
        if (idx == n - 1) off[n] = run;
    }
}

// ---------------- bucket placement: ssorted[off[d] + pos] = src (4 types, grid.y) ----
__global__ void place4_kernel(const int* __restrict__ s0, const int* __restrict__ s1,
                              const int* __restrict__ s2, const int* __restrict__ s3,
                              const int* __restrict__ d0, const int* __restrict__ d1,
                              const int* __restrict__ d2, const int* __restrict__ d3,
                              const int* __restrict__ o0, const int* __restrict__ o1,
                              const int* __restrict__ o2, const int* __restrict__ o3,
                              int* u0, int* u1, int* u2, int* u3,
                              int* __restrict__ ssorted, int E) {
    int i = blockIdx.x * blockDim.x + threadIdx.x;
    if (i >= E) return;
    int e = blockIdx.y;
    const int* src = (e == 0) ? s0 : (e == 1) ? s1 : (e == 2) ? s2 : s3;
    const int* dst = (e == 0) ? d0 : (e == 1) ? d1 : (e == 2) ? d2 : d3;
    const int* off = (e == 0) ? o0 : (e == 1) ? o1 : (e == 2) ? o2 : o3;
    int* cur = (e == 0) ? u0 : (e == 1) ? u1 : (e == 2) ? u2 : u3;
    int d = dst[i];
    int p = atomicAdd(&cur[d], 1);
    ssorted[off[d] + p] = src[i];
}

// ---------------- gather-mean: agg[d] = mean_{s in N(d)} hsrc[s] (16 lanes/node) ----
__global__ void gather_agg_kernel(const float* __restrict__ hsrc, const int* __restrict__ off,
                                  const int* __restrict__ ssorted, const float* __restrict__ rdeg,
                                  float* __restrict__ agg, int N) {
    int t = blockIdx.x * blockDim.x + threadIdx.x;
    int d = t >> 4, q = t & 15;
    if (d >= N) return;
    int lo = off[d], hi = off[d + 1];
    float a0x = 0, a0y = 0, a0z = 0, a0w = 0;
    float a1x = 0, a1y = 0, a1z = 0, a1w = 0;
    int j = lo;
    for (; j + 2 <= hi; j += 2) {
        int s0 = ssorted[j], s1 = ssorted[j + 1];
        const float4 v0 = *reinterpret_cast<const float4*>(hsrc + (size_t)s0 * HD + q * 4);
        const float4 v1 = *reinterpret_cast<const float4*>(hsrc + (size_t)s1 * HD + q * 4);
        a0x += v0.x; a0y += v0.y; a0z += v0.z; a0w += v0.w;
        a1x += v1.x; a1y += v1.y; a1z += v1.z; a1w += v1.w;
    }
    if (j < hi) {
        int s0 = ssorted[j];
        const float4 v0 = *reinterpret_cast<const float4*>(hsrc + (size_t)s0 * HD + q * 4);
        a0x += v0.x; a0y += v0.y; a0z += v0.z; a0w += v0.w;
    }
    float r = rdeg[d];
    float4 o;
    o.x = (a0x + a1x) * r; o.y = (a0y + a1y) * r; o.z = (a0z + a1z) * r; o.w = (a0w + a1w) * r;
    *reinterpret_cast<float4*>(agg + (size_t)d * HD + q * 4) = o;
}

// ---------------- SAGE out: hn += agg @ Wl + bl + h_dst @ Wr (64 rows/block) --------
#define SO_ROWS 64
__global__ void sage_out_kernel(const float* __restrict__ agg,
                                const float* __restrict__ hdst,
                                const float* __restrict__ Wl, const float* __restrict__ bl,
                                const float* __restrict__ Wr,
                                float* __restrict__ hn, int N) {
    __shared__ float sWl[HD * HD];
    __shared__ float sWr[HD * HD];
    int t = threadIdx.x;
    for (int i = t; i < HD * HD; i += 256) { sWl[i] = Wl[i]; sWr[i] = Wr[i]; }
    __syncthreads();
    int c = t & 63;
    int rbase = blockIdx.x * SO_ROWS + (t >> 6);
    float blc = bl[c];
    for (int rr = 0; rr < SO_ROWS; rr += 4) {
        int r = rbase + rr;
        if (r >= N) break;
        const float* ar = agg + (size_t)r * HD;
        const float* hr = hdst + (size_t)r * HD;
        float acca = 0.0f, acch = 0.0f;
#pragma unroll 8
        for (int k = 0; k < HD; ++k) {
            acca = fmaf(ar[k], sWl[k * HD + c], acca);
            acch = fmaf(hr[k], sWr[k * HD + c], acch);
        }
        hn[(size_t)r * HD + c] += acca + blc + acch;
    }
}

// ---------------- residual + LayerNorm + ELU (one wave per row) ----------------
__global__ void ln_elu_kernel(float* __restrict__ h, const float* __restrict__ hn,
                              const float* __restrict__ g, const float* __restrict__ b, int N) {
    int t = threadIdx.x;
    int r = blockIdx.x * 4 + (t >> 6);
    int c = t & 63;
    if (r >= N) return;
    float v = h[(size_t)r * HD + c] + hn[(size_t)r * HD + c];
    float s = v;
#pragma unroll
    for (int o = 32; o > 0; o >>= 1) s += __shfl_xor(s, o, 64);
    float mean = s * (1.0f / 64.0f);
    float d = v - mean;
    float sq = d * d;
#pragma unroll
    for (int o = 32; o > 0; o >>= 1) sq += __shfl_xor(sq, o, 64);
    float var = sq * (1.0f / 64.0f);
    float y = d * rsqrtf(var + 1e-5f) * g[c] + b[c];
    h[(size_t)r * HD + c] = elu_f(y);
}

// ---------------- cox head: out = elu(h @ W1 + b1) @ W2 + b2 ----------------
__global__ void cox_kernel(const float* __restrict__ hp,
                           const float* __restrict__ W1, const float* __restrict__ b1,
                           const float* __restrict__ W2, const float* __restrict__ b2,
                           float* __restrict__ out, int N) {
    __shared__ float sW1[HD * 32];
    __shared__ float sW2[32];
    int t = threadIdx.x;
    for (int i = t; i < HD * 32; i += 256) sW1[i] = W1[i];
    if (t < 32) sW2[t] = W2[t];
    __syncthreads();
    int r = blockIdx.x * 8 + (t >> 5);
    int c = t & 31;
    if (r >= N) return;
    const float* hr = hp + (size_t)r * HD;
    float acc = b1[c];
#pragma unroll 8
    for (int k = 0; k < HD; ++k) acc = fmaf(hr[k], sW1[k * 32 + c], acc);
    float z = elu_f(acc) * sW2[c];
#pragma unroll
    for (int o = 16; o > 0; o >>= 1) z += __shfl_xor(z, o, 32);
    if (c == 0) out[r] = z + b2[0];
}

extern "C" void kernel_launch(void* const* d_in, const int* in_sizes, int n_in,
                              void* d_out, int out_size, void* d_ws, size_t ws_size,
                              hipStream_t stream) {
    const float* x_gene    = (const float*)d_in[0];
    const float* x_patient = (const float*)d_in[1];
    const float* x_group   = (const float*)d_in[2];
    const int* srcs[4] = {(const int*)d_in[3], (const int*)d_in[5], (const int*)d_in[7], (const int*)d_in[9]};
    const int* dsts[4] = {(const int*)d_in[4], (const int*)d_in[6], (const int*)d_in[8], (const int*)d_in[10]};
    const float* enc_gene_W    = (const float*)d_in[11];
    const float* enc_gene_b    = (const float*)d_in[12];
    const float* enc_patient_W = (const float*)d_in[13];
    const float* enc_patient_b = (const float*)d_in[14];
    const float* enc_group_W   = (const float*)d_in[15];
    const float* enc_group_b   = (const float*)d_in[16];
    const float* convW_l = (const float*)d_in[17];  // [2,4,64,64]
    const float* convb_l = (const float*)d_in[18];  // [2,4,64]
    const float* convW_r = (const float*)d_in[19];  // [2,4,64,64]
    const float* ln_gamma = (const float*)d_in[20]; // [2,3,64]
    const float* ln_beta  = (const float*)d_in[21];
    const float* coxW1 = (const float*)d_in[22];
    const float* coxb1 = (const float*)d_in[23];
    const float* coxW2 = (const float*)d_in[24];
    const float* coxb2 = (const float*)d_in[25];
    float* out = (float*)d_out;

    const int n_gene    = in_sizes[0] / 11;
    const int n_patient = in_sizes[1] / 3;
    const int n_group   = in_sizes[2] / 4;
    const int E         = in_sizes[3];

    // ---- workspace layout ----
    float* wf = (float*)d_ws;
    float* h_gene  = wf;                          wf += (size_t)n_gene * HD;
    float* h_pat   = wf;                          wf += (size_t)n_patient * HD;
    float* h_grp   = wf;                          wf += (size_t)n_group * HD;
    float* hn_base = wf;
    float* hn_gene = wf;                          wf += (size_t)n_gene * HD;
    float* hn_pat  = wf;                          wf += (size_t)n_patient * HD;
    float* hn_grp  = wf;                          wf += (size_t)n_group * HD;
    float* agg     = wf;                          wf += (size_t)n_patient * HD; // max dst count
    float* rdeg_base = wf;
    float* rdeg[4];
    rdeg[0] = wf; wf += n_patient;
    rdeg[1] = wf; wf += n_gene;
    rdeg[2] = wf; wf += n_group;
    rdeg[3] = wf; wf += n_gene;

    int* wi = (int*)wf;
    int* cnt_base = wi;                           // concatenated counts / cursors
    int* cnt[4];
    cnt[0] = wi; wi += n_patient;
    cnt[1] = wi; wi += n_gene;
    cnt[2] = wi; wi += n_group;
    cnt[3] = wi; wi += n_gene;
    // single concatenated offsets array (global exclusive scan), +1 sentinel
    int* off_base = wi;
    int* off[4];
    off[0] = wi; wi += n_patient;
    off[1] = wi; wi += n_gene;
    off[2] = wi; wi += n_group;
    off[3] = wi; wi += n_gene;
    wi += 1;                                      // off_base[deg_total] sentinel
    int* ssorted = wi;  wi += (size_t)E * 4;      // single 4E array (type e at [e*E,(e+1)*E))
    int* bsum = wi;     wi += 1024;

    const size_t hn_total  = ((size_t)n_gene + n_patient + n_group) * HD;
    const int    deg_total = n_patient + n_gene + n_group + n_gene;

    const float* e_hsrc[4] = {h_gene, h_pat, h_gene, h_grp};
    const float* e_hdst[4] = {h_pat, h_gene, h_grp, h_gene};
    float*       e_hn[4]   = {hn_pat, hn_gene, hn_grp, hn_gene};
    const int    e_nd[4]   = {n_patient, n_gene, n_group, n_gene};
    float*    nt_h[3]  = {h_gene, h_pat, h_grp};
    float*    nt_hn[3] = {hn_gene, hn_pat, hn_grp};
    const int nt_n[3]  = {n_gene, n_patient, n_group};

    // ---- encoders ----
    encode_kernel<11><<<(n_gene + 3) / 4, 256, 0, stream>>>(x_gene, enc_gene_W, enc_gene_b, h_gene, n_gene);
    encode_kernel<3><<<(n_patient + 3) / 4, 256, 0, stream>>>(x_patient, enc_patient_W, enc_patient_b, h_pat, n_patient);
    encode_kernel<4><<<(n_group + 3) / 4, 256, 0, stream>>>(x_group, enc_group_W, enc_group_b, h_grp, n_group);

    // ---- CSR build (layer-invariant, built once) ----
    hipMemsetAsync(cnt_base, 0, (size_t)deg_total * sizeof(int), stream);
    {
        dim3 g((E + 255) / 256, 4);
        count_deg4_kernel<<<g, 256, 0, stream>>>(dsts[0], dsts[1], dsts[2], dsts[3],
                                                 cnt[0], cnt[1], cnt[2], cnt[3], E);
    }
    rdeg_kernel<<<(deg_total + 255) / 256, 256, 0, stream>>>(cnt_base, rdeg_base, deg_total);
    {
        int nb = (deg_total + SCAN_EPB - 1) / SCAN_EPB;
        scan_block_sum<<<nb, SCAN_TPB, 0, stream>>>(cnt_base, bsum, deg_total);
        scan_bsum_kernel<<<1, 1024, 0, stream>>>(bsum, nb);
        scan_write_kernel<<<nb, SCAN_TPB, 0, stream>>>(cnt_base, bsum, off_base, deg_total);
    }
    hipMemsetAsync(cnt_base, 0, (size_t)deg_total * sizeof(int), stream);  // reuse as cursors
    {
        dim3 g((E + 255) / 256, 4);
        place4_kernel<<<g, 256, 0, stream>>>(srcs[0], srcs[1], srcs[2], srcs[3],
                                             dsts[0], dsts[1], dsts[2], dsts[3],
                                             off[0], off[1], off[2], off[3],
                                             cnt[0], cnt[1], cnt[2], cnt[3],
                                             ssorted, E);
    }

    // ---- 2 GNN layers ----
    for (int layer = 0; layer < 2; ++layer) {
        hipMemsetAsync(hn_base, 0, hn_total * sizeof(float), stream);
        for (int e = 0; e < 4; ++e) {
            const int nd = e_nd[e];
            gather_agg_kernel<<<((size_t)nd * 16 + 255) / 256, 256, 0, stream>>>(
                e_hsrc[e], off[e], ssorted, rdeg[e], agg, nd);
            const int pe = layer * 4 + e;
            sage_out_kernel<<<(nd + SO_ROWS - 1) / SO_ROWS, 256, 0, stream>>>(
                agg, e_hdst[e],
                convW_l + (size_t)pe * HD * HD, convb_l + (size_t)pe * HD,
                convW_r + (size_t)pe * HD * HD, e_hn[e], nd);
        }
        for (int ni = 0; ni < 3; ++ni) {
            const int pn = layer * 3 + ni;
            ln_elu_kernel<<<(nt_n[ni] + 3) / 4, 256, 0, stream>>>(
                nt_h[ni], nt_hn[ni], ln_gamma + (size_t)pn * HD, ln_beta + (size_t)pn * HD, nt_n[ni]);
        }
    }

    // ---- cox head ----
    cox_kernel<<<(n_patient + 7) / 8, 256, 0, stream>>>(h_pat, coxW1, coxb1, coxW2, coxb2, out, n_patient);
}

// Round 4
// 1143.586 us; speedup vs baseline: 6.6485x; 1.1633x over previous
//
#include <hip/hip_runtime.h>

#define HD 64
#define NPART 8
#define NCHUNK 32

__device__ __forceinline__ float elu_f(float x) { return x > 0.0f ? x : __expf(x) - 1.0f; }

// ---------------- encoders: h = elu(x @ W + b), x:[N,FIN], W:[FIN,64] ----------------
template<int FIN>
__global__ void encode_kernel(const float* __restrict__ x, const float* __restrict__ W,
                              const float* __restrict__ b, float* __restrict__ h, int N) {
    __shared__ float sW[FIN * HD];
    int t = threadIdx.x;
    for (int i = t; i < FIN * HD; i += 256) sW[i] = W[i];
    __syncthreads();
    int r = blockIdx.x * 4 + (t >> 6);
    int c = t & 63;
    if (r >= N) return;
    float acc = b[c];
#pragma unroll
    for (int k = 0; k < FIN; ++k) acc = fmaf(x[r * FIN + k], sW[k * HD + c], acc);
    h[r * HD + c] = elu_f(acc);
}

// ---- XCD-partitioned degree histogram (LDS-privatized), 4 types via grid.y --------
// partition p = blockIdx.x % NPART owns dst range [nd*p/8, nd*(p+1)/8); each block
// scans one edge chunk and counts only its range into LDS, then flushes once.
__global__ void count_part_kernel(const int* __restrict__ d0, const int* __restrict__ d1,
                                  const int* __restrict__ d2, const int* __restrict__ d3,
                                  int* c0, int* c1, int* c2, int* c3,
                                  int nd0, int nd1, int nd2, int nd3, int E) {
    int e = blockIdx.y;
    const int* dst = (e == 0) ? d0 : (e == 1) ? d1 : (e == 2) ? d2 : d3;
    int* cnt = (e == 0) ? c0 : (e == 1) ? c1 : (e == 2) ? c2 : c3;
    int nd   = (e == 0) ? nd0 : (e == 1) ? nd1 : (e == 2) ? nd2 : nd3;
    int p = blockIdx.x % NPART;
    int chunk = blockIdx.x / NPART;
    int dlo = (int)((long long)nd * p / NPART);
    int dhi = (int)((long long)nd * (p + 1) / NPART);
    int range = dhi - dlo;
    extern __shared__ int hist[];
    for (int i = threadIdx.x; i < range; i += blockDim.x) hist[i] = 0;
    __syncthreads();
    int per = (E + NCHUNK - 1) / NCHUNK;
    int lo = chunk * per, hi = min(lo + per, E);
    for (int i = lo + threadIdx.x; i < hi; i += blockDim.x) {
        int d = dst[i];
        if (d >= dlo && d < dhi) atomicAdd(&hist[d - dlo], 1);
    }
    __syncthreads();
    for (int i = threadIdx.x; i < range; i += blockDim.x) {
        int v = hist[i];
        if (v) atomicAdd(&cnt[dlo + i], v);
    }
}

// ---------------- multi-block exclusive scan over concatenated counts ----------------
#define SCAN_TPB 256
#define SCAN_EPT 8
#define SCAN_EPB (SCAN_TPB * SCAN_EPT)  // 2048

__global__ void scan_block_sum(const int* __restrict__ cnt, int* __restrict__ bsum, int n) {
    int base = blockIdx.x * SCAN_EPB;
    int t = threadIdx.x;
    int sum = 0;
    for (int i = t; i < SCAN_EPB; i += SCAN_TPB) {
        int idx = base + i;
        if (idx < n) sum += cnt[idx];
    }
    __shared__ int s[SCAN_TPB];
    s[t] = sum;
    __syncthreads();
    for (int ofs = SCAN_TPB / 2; ofs > 0; ofs >>= 1) {
        if (t < ofs) s[t] += s[t + ofs];
        __syncthreads();
    }
    if (t == 0) bsum[blockIdx.x] = s[0];
}

__global__ __launch_bounds__(1024) void scan_bsum_kernel(int* bsum, int nb) {
    __shared__ int s[1024];
    int t = threadIdx.x;
    s[t] = (t < nb) ? bsum[t] : 0;
    __syncthreads();
    for (int ofs = 1; ofs < 1024; ofs <<= 1) {
        int v = (t >= ofs) ? s[t - ofs] : 0;
        __syncthreads();
        s[t] += v;
        __syncthreads();
    }
    if (t < nb) bsum[t] = (t == 0) ? 0 : s[t - 1];
}

__global__ void scan_write_kernel(const int* __restrict__ cnt, const int* __restrict__ bsum,
                                  int* __restrict__ off, int n) {
    int base = blockIdx.x * SCAN_EPB;
    int t = threadIdx.x;
    int lo = base + t * SCAN_EPT;
    int vals[SCAN_EPT];
    int sum = 0;
#pragma unroll
    for (int i = 0; i < SCAN_EPT; ++i) {
        int idx = lo + i;
        vals[i] = (idx < n) ? cnt[idx] : 0;
        sum += vals[i];
    }
    __shared__ int s[SCAN_TPB];
    s[t] = sum;
    __syncthreads();
    for (int ofs = 1; ofs < SCAN_TPB; ofs <<= 1) {
        int v = (t >= ofs) ? s[t - ofs] : 0;
        __syncthreads();
        s[t] += v;
        __syncthreads();
    }
    int run = bsum[blockIdx.x] + ((t == 0) ? 0 : s[t - 1]);
#pragma unroll
    for (int i = 0; i < SCAN_EPT; ++i) {
        int idx = lo + i;
        if (idx < n) off[idx] = run;
        run += vals[i];
        if (idx == n - 1) off[n] = run;
    }
}

// ---- XCD-partitioned bucket placement: ssorted[off[d]+pos] = src ------------------
__global__ void place_part_kernel(const int* __restrict__ s0, const int* __restrict__ s1,
                                  const int* __restrict__ s2, const int* __restrict__ s3,
                                  const int* __restrict__ d0, const int* __restrict__ d1,
                                  const int* __restrict__ d2, const int* __restrict__ d3,
                                  const int* __restrict__ o0, const int* __restrict__ o1,
                                  const int* __restrict__ o2, const int* __restrict__ o3,
                                  int* u0, int* u1, int* u2, int* u3,
                                  int nd0, int nd1, int nd2, int nd3,
                                  int* __restrict__ ssorted, int E) {
    int e = blockIdx.y;
    const int* src = (e == 0) ? s0 : (e == 1) ? s1 : (e == 2) ? s2 : s3;
    const int* dst = (e == 0) ? d0 : (e == 1) ? d1 : (e == 2) ? d2 : d3;
    const int* off = (e == 0) ? o0 : (e == 1) ? o1 : (e == 2) ? o2 : o3;
    int* cur = (e == 0) ? u0 : (e == 1) ? u1 : (e == 2) ? u2 : u3;
    int nd  = (e == 0) ? nd0 : (e == 1) ? nd1 : (e == 2) ? nd2 : nd3;
    int p = blockIdx.x % NPART;
    int chunk = blockIdx.x / NPART;
    int dlo = (int)((long long)nd * p / NPART);
    int dhi = (int)((long long)nd * (p + 1) / NPART);
    int per = (E + NCHUNK - 1) / NCHUNK;
    int lo = chunk * per, hi = min(lo + per, E);
    for (int i = lo + threadIdx.x; i < hi; i += blockDim.x) {
        int d = dst[i];
        if (d >= dlo && d < dhi) {
            int pos = atomicAdd(&cur[d], 1);
            ssorted[off[d] + pos] = src[i];
        }
    }
}

// ---------------- gather-mean: agg[d] = mean_{s in N(d)} hsrc[s] (16 lanes/node) ----
__global__ void gather_agg_kernel(const float* __restrict__ hsrc, const int* __restrict__ off,
                                  const int* __restrict__ ssorted,
                                  float* __restrict__ agg, int N) {
    int t = blockIdx.x * blockDim.x + threadIdx.x;
    int d = t >> 4, q = t & 15;
    if (d >= N) return;
    int lo = off[d], hi = off[d + 1];
    float a0x = 0, a0y = 0, a0z = 0, a0w = 0;
    float a1x = 0, a1y = 0, a1z = 0, a1w = 0;
    int j = lo;
    for (; j + 2 <= hi; j += 2) {
        int s0 = ssorted[j], s1 = ssorted[j + 1];
        const float4 v0 = *reinterpret_cast<const float4*>(hsrc + (size_t)s0 * HD + q * 4);
        const float4 v1 = *reinterpret_cast<const float4*>(hsrc + (size_t)s1 * HD + q * 4);
        a0x += v0.x; a0y += v0.y; a0z += v0.z; a0w += v0.w;
        a1x += v1.x; a1y += v1.y; a1z += v1.z; a1w += v1.w;
    }
    if (j < hi) {
        int s0 = ssorted[j];
        const float4 v0 = *reinterpret_cast<const float4*>(hsrc + (size_t)s0 * HD + q * 4);
        a0x += v0.x; a0y += v0.y; a0z += v0.z; a0w += v0.w;
    }
    float r = 1.0f / fmaxf((float)(hi - lo), 1.0f);
    float4 o;
    o.x = (a0x + a1x) * r; o.y = (a0y + a1y) * r; o.z = (a0z + a1z) * r; o.w = (a0w + a1w) * r;
    *reinterpret_cast<float4*>(agg + (size_t)d * HD + q * 4) = o;
}

// ---------------- SAGE out: hn (=|+=) agg @ Wl + bl + h_dst @ Wr (64 rows/block) ----
#define SO_ROWS 64
template<bool ACCUM>
__global__ void sage_out_kernel(const float* __restrict__ agg,
                                const float* __restrict__ hdst,
                                const float* __restrict__ Wl, const float* __restrict__ bl,
                                const float* __restrict__ Wr,
                                float* __restrict__ hn, int N) {
    __shared__ float sWl[HD * HD];
    __shared__ float sWr[HD * HD];
    int t = threadIdx.x;
    for (int i = t; i < HD * HD; i += 256) { sWl[i] = Wl[i]; sWr[i] = Wr[i]; }
    __syncthreads();
    int c = t & 63;
    int rbase = blockIdx.x * SO_ROWS + (t >> 6);
    float blc = bl[c];
    for (int rr = 0; rr < SO_ROWS; rr += 4) {
        int r = rbase + rr;
        if (r >= N) break;
        const float* ar = agg + (size_t)r * HD;
        const float* hr = hdst + (size_t)r * HD;
        float acca = 0.0f, acch = 0.0f;
#pragma unroll 8
        for (int k = 0; k < HD; ++k) {
            acca = fmaf(ar[k], sWl[k * HD + c], acca);
            acch = fmaf(hr[k], sWr[k * HD + c], acch);
        }
        float v = acca + blc + acch;
        if (ACCUM) hn[(size_t)r * HD + c] += v;
        else       hn[(size_t)r * HD + c] = v;
    }
}

// ---------------- residual + LayerNorm + ELU (one wave per row) ----------------
__global__ void ln_elu_kernel(float* __restrict__ h, const float* __restrict__ hn,
                              const float* __restrict__ g, const float* __restrict__ b, int N) {
    int t = threadIdx.x;
    int r = blockIdx.x * 4 + (t >> 6);
    int c = t & 63;
    if (r >= N) return;
    float v = h[(size_t)r * HD + c] + hn[(size_t)r * HD + c];
    float s = v;
#pragma unroll
    for (int o = 32; o > 0; o >>= 1) s += __shfl_xor(s, o, 64);
    float mean = s * (1.0f / 64.0f);
    float d = v - mean;
    float sq = d * d;
#pragma unroll
    for (int o = 32; o > 0; o >>= 1) sq += __shfl_xor(sq, o, 64);
    float var = sq * (1.0f / 64.0f);
    float y = d * rsqrtf(var + 1e-5f) * g[c] + b[c];
    h[(size_t)r * HD + c] = elu_f(y);
}

// ---------------- cox head: out = elu(h @ W1 + b1) @ W2 + b2 ----------------
__global__ void cox_kernel(const float* __restrict__ hp,
                           const float* __restrict__ W1, const float* __restrict__ b1,
                           const float* __restrict__ W2, const float* __restrict__ b2,
                           float* __restrict__ out, int N) {
    __shared__ float sW1[HD * 32];
    __shared__ float sW2[32];
    int t = threadIdx.x;
    for (int i = t; i < HD * 32; i += 256) sW1[i] = W1[i];
    if (t < 32) sW2[t] = W2[t];
    __syncthreads();
    int r = blockIdx.x * 8 + (t >> 5);
    int c = t & 31;
    if (r >= N) return;
    const float* hr = hp + (size_t)r * HD;
    float acc = b1[c];
#pragma unroll 8
    for (int k = 0; k < HD; ++k) acc = fmaf(hr[k], sW1[k * 32 + c], acc);
    float z = elu_f(acc) * sW2[c];
#pragma unroll
    for (int o = 16; o > 0; o >>= 1) z += __shfl_xor(z, o, 32);
    if (c == 0) out[r] = z + b2[0];
}

extern "C" void kernel_launch(void* const* d_in, const int* in_sizes, int n_in,
                              void* d_out, int out_size, void* d_ws, size_t ws_size,
                              hipStream_t stream) {
    const float* x_gene    = (const float*)d_in[0];
    const float* x_patient = (const float*)d_in[1];
    const float* x_group   = (const float*)d_in[2];
    const int* srcs[4] = {(const int*)d_in[3], (const int*)d_in[5], (const int*)d_in[7], (const int*)d_in[9]};
    const int* dsts[4] = {(const int*)d_in[4], (const int*)d_in[6], (const int*)d_in[8], (const int*)d_in[10]};
    const float* enc_gene_W    = (const float*)d_in[11];
    const float* enc_gene_b    = (const float*)d_in[12];
    const float* enc_patient_W = (const float*)d_in[13];
    const float* enc_patient_b = (const float*)d_in[14];
    const float* enc_group_W   = (const float*)d_in[15];
    const float* enc_group_b   = (const float*)d_in[16];
    const float* convW_l = (const float*)d_in[17];  // [2,4,64,64]
    const float* convb_l = (const float*)d_in[18];  // [2,4,64]
    const float* convW_r = (const float*)d_in[19];  // [2,4,64,64]
    const float* ln_gamma = (const float*)d_in[20]; // [2,3,64]
    const float* ln_beta  = (const float*)d_in[21];
    const float* coxW1 = (const float*)d_in[22];
    const float* coxb1 = (const float*)d_in[23];
    const float* coxW2 = (const float*)d_in[24];
    const float* coxb2 = (const float*)d_in[25];
    float* out = (float*)d_out;

    const int n_gene    = in_sizes[0] / 11;
    const int n_patient = in_sizes[1] / 3;
    const int n_group   = in_sizes[2] / 4;
    const int E         = in_sizes[3];

    // ---- workspace layout ----
    float* wf = (float*)d_ws;
    float* h_gene  = wf;                          wf += (size_t)n_gene * HD;
    float* h_pat   = wf;                          wf += (size_t)n_patient * HD;
    float* h_grp   = wf;                          wf += (size_t)n_group * HD;
    float* hn_gene = wf;                          wf += (size_t)n_gene * HD;
    float* hn_pat  = wf;                          wf += (size_t)n_patient * HD;
    float* hn_grp  = wf;                          wf += (size_t)n_group * HD;
    float* agg     = wf;                          wf += (size_t)n_patient * HD; // max dst count

    int* wi = (int*)wf;
    int* cnt_base = wi;                           // concatenated counts / cursors
    int* cnt[4];
    cnt[0] = wi; wi += n_patient;
    cnt[1] = wi; wi += n_gene;
    cnt[2] = wi; wi += n_group;
    cnt[3] = wi; wi += n_gene;
    int* off_base = wi;                           // concatenated offsets (global exscan)
    int* off[4];
    off[0] = wi; wi += n_patient;
    off[1] = wi; wi += n_gene;
    off[2] = wi; wi += n_group;
    off[3] = wi; wi += n_gene;
    wi += 1;                                      // sentinel off_base[deg_total]
    int* ssorted = wi;  wi += (size_t)E * 4;      // single 4E array
    int* bsum = wi;     wi += 1024;

    const int deg_total = n_patient + n_gene + n_group + n_gene;

    const float* e_hsrc[4] = {h_gene, h_pat, h_gene, h_grp};
    const float* e_hdst[4] = {h_pat, h_gene, h_grp, h_gene};
    float*       e_hn[4]   = {hn_pat, hn_gene, hn_grp, hn_gene};
    const int    e_nd[4]   = {n_patient, n_gene, n_group, n_gene};
    float*    nt_h[3]  = {h_gene, h_pat, h_grp};
    float*    nt_hn[3] = {hn_gene, hn_pat, hn_grp};
    const int nt_n[3]  = {n_gene, n_patient, n_group};

    // ---- encoders ----
    encode_kernel<11><<<(n_gene + 3) / 4, 256, 0, stream>>>(x_gene, enc_gene_W, enc_gene_b, h_gene, n_gene);
    encode_kernel<3><<<(n_patient + 3) / 4, 256, 0, stream>>>(x_patient, enc_patient_W, enc_patient_b, h_pat, n_patient);
    encode_kernel<4><<<(n_group + 3) / 4, 256, 0, stream>>>(x_group, enc_group_W, enc_group_b, h_grp, n_group);

    // ---- CSR build (layer-invariant, built once) ----
    int max_nd = n_patient > n_gene ? n_patient : n_gene;
    if (n_group > max_nd) max_nd = n_group;
    size_t hist_bytes = (size_t)((max_nd + NPART - 1) / NPART) * sizeof(int);

    hipMemsetAsync(cnt_base, 0, (size_t)deg_total * sizeof(int), stream);
    {
        dim3 g(NPART * NCHUNK, 4);
        count_part_kernel<<<g, 256, hist_bytes, stream>>>(
            dsts[0], dsts[1], dsts[2], dsts[3],
            cnt[0], cnt[1], cnt[2], cnt[3],
            e_nd[0], e_nd[1], e_nd[2], e_nd[3], E);
    }
    {
        int nb = (deg_total + SCAN_EPB - 1) / SCAN_EPB;
        scan_block_sum<<<nb, SCAN_TPB, 0, stream>>>(cnt_base, bsum, deg_total);
        scan_bsum_kernel<<<1, 1024, 0, stream>>>(bsum, nb);
        scan_write_kernel<<<nb, SCAN_TPB, 0, stream>>>(cnt_base, bsum, off_base, deg_total);
    }
    hipMemsetAsync(cnt_base, 0, (size_t)deg_total * sizeof(int), stream);  // reuse as cursors
    {
        dim3 g(NPART * NCHUNK, 4);
        place_part_kernel<<<g, 256, 0, stream>>>(
            srcs[0], srcs[1], srcs[2], srcs[3],
            dsts[0], dsts[1], dsts[2], dsts[3],
            off[0], off[1], off[2], off[3],
            cnt[0], cnt[1], cnt[2], cnt[3],
            e_nd[0], e_nd[1], e_nd[2], e_nd[3],
            ssorted, E);
    }

    // ---- 2 GNN layers ----
    for (int layer = 0; layer < 2; ++layer) {
        for (int e = 0; e < 4; ++e) {
            const int nd = e_nd[e];
            gather_agg_kernel<<<((size_t)nd * 16 + 255) / 256, 256, 0, stream>>>(
                e_hsrc[e], off[e], ssorted, agg, nd);
            const int pe = layer * 4 + e;
            if (e == 3)
                sage_out_kernel<true><<<(nd + SO_ROWS - 1) / SO_ROWS, 256, 0, stream>>>(
                    agg, e_hdst[e],
                    convW_l + (size_t)pe * HD * HD, convb_l + (size_t)pe * HD,
                    convW_r + (size_t)pe * HD * HD, e_hn[e], nd);
            else
                sage_out_kernel<false><<<(nd + SO_ROWS - 1) / SO_ROWS, 256, 0, stream>>>(
                    agg, e_hdst[e],
                    convW_l + (size_t)pe * HD * HD, convb_l + (size_t)pe * HD,
                    convW_r + (size_t)pe * HD * HD, e_hn[e], nd);
        }
        for (int ni = 0; ni < 3; ++ni) {
            const int pn = layer * 3 + ni;
            ln_elu_kernel<<<(nt_n[ni] + 3) / 4, 256, 0, stream>>>(
                nt_h[ni], nt_hn[ni], ln_gamma + (size_t)pn * HD, ln_beta + (size_t)pn * HD, nt_n[ni]);
        }
    }

    // ---- cox head ----
    cox_kernel<<<(n_patient + 7) / 8, 256, 0, stream>>>(h_pat, coxW1, coxb1, coxW2, coxb2, out, n_patient);
}

// Round 5
// 1129.994 us; speedup vs baseline: 6.7285x; 1.0120x over previous
//
#include <hip/hip_runtime.h>

#define HD 64
#define NPART 8

__device__ __forceinline__ float elu_f(float x) { return x > 0.0f ? x : __expf(x) - 1.0f; }

// ---------------- encoders: h = elu(x @ W + b), x:[N,FIN], W:[FIN,64] ----------------
template<int FIN>
__global__ void encode_kernel(const float* __restrict__ x, const float* __restrict__ W,
                              const float* __restrict__ b, float* __restrict__ h, int N) {
    __shared__ float sW[FIN * HD];
    int t = threadIdx.x;
    for (int i = t; i < FIN * HD; i += 256) sW[i] = W[i];
    __syncthreads();
    int r = blockIdx.x * 4 + (t >> 6);
    int c = t & 63;
    if (r >= N) return;
    float acc = b[c];
#pragma unroll
    for (int k = 0; k < FIN; ++k) acc = fmaf(x[r * FIN + k], sW[k * HD + c], acc);
    h[r * HD + c] = elu_f(acc);
}

// ---- phase A: bin edges into per-(type,partition) (dst,src) pair segments --------
// Reads edges ONCE; coalesced-ish segment writes; LDS cursors + 1 reservation/blk.
__global__ void bin_kernel(const int* __restrict__ s0, const int* __restrict__ s1,
                           const int* __restrict__ s2, const int* __restrict__ s3,
                           const int* __restrict__ d0, const int* __restrict__ d1,
                           const int* __restrict__ d2, const int* __restrict__ d3,
                           int nd0, int nd1, int nd2, int nd3,
                           int2* __restrict__ pairs, int cap, int* __restrict__ gcur, int E) {
    int e = blockIdx.y;
    const int* src = (e == 0) ? s0 : (e == 1) ? s1 : (e == 2) ? s2 : s3;
    const int* dst = (e == 0) ? d0 : (e == 1) ? d1 : (e == 2) ? d2 : d3;
    int nd  = (e == 0) ? nd0 : (e == 1) ? nd1 : (e == 2) ? nd2 : nd3;
    int2* tp = pairs + (size_t)e * NPART * cap;
    int* tc = gcur + e * NPART;
    __shared__ int sbase[NPART], scur[NPART];
    int per = (E + gridDim.x - 1) / gridDim.x;
    int lo = blockIdx.x * per, hi = min(lo + per, E);
    if (threadIdx.x < NPART) scur[threadIdx.x] = 0;
    __syncthreads();
    for (int i = lo + threadIdx.x; i < hi; i += blockDim.x) {
        int p = (int)(((long long)dst[i] * NPART) / nd);
        atomicAdd(&scur[p], 1);
    }
    __syncthreads();
    if (threadIdx.x < NPART) {
        sbase[threadIdx.x] = atomicAdd(&tc[threadIdx.x], scur[threadIdx.x]);
        scur[threadIdx.x] = 0;
    }
    __syncthreads();
    for (int i = lo + threadIdx.x; i < hi; i += blockDim.x) {
        int d = dst[i];
        int p = (int)(((long long)d * NPART) / nd);
        int pos = sbase[p] + atomicAdd(&scur[p], 1);
        tp[(size_t)p * cap + pos] = make_int2(d, src[i]);
    }
}

// ---- phase B1: per-partition LDS histogram from binned pairs ----------------------
__global__ void countB_kernel(const int2* __restrict__ pairs, int cap,
                              const int* __restrict__ gcur,
                              int* c0, int* c1, int* c2, int* c3,
                              int nd0, int nd1, int nd2, int nd3) {
    int e = blockIdx.y;
    int* cnt = (e == 0) ? c0 : (e == 1) ? c1 : (e == 2) ? c2 : c3;
    int nd   = (e == 0) ? nd0 : (e == 1) ? nd1 : (e == 2) ? nd2 : nd3;
    int p = blockIdx.x % NPART;
    int chunk = blockIdx.x / NPART;
    int nchunk = gridDim.x / NPART;
    int dlo = (int)((long long)nd * p / NPART);
    int dhi = (int)((long long)nd * (p + 1) / NPART);
    int range = dhi - dlo;
    extern __shared__ int hist[];
    for (int i = threadIdx.x; i < range; i += blockDim.x) hist[i] = 0;
    __syncthreads();
    int len = gcur[e * NPART + p];
    const int2* seg = pairs + ((size_t)e * NPART + p) * cap;
    int per = (len + nchunk - 1) / nchunk;
    int lo = chunk * per, hi = min(lo + per, len);
    for (int i = lo + threadIdx.x; i < hi; i += blockDim.x)
        atomicAdd(&hist[seg[i].x - dlo], 1);
    __syncthreads();
    for (int i = threadIdx.x; i < range; i += blockDim.x) {
        int v = hist[i];
        if (v) atomicAdd(&cnt[dlo + i], v);
    }
}

// ---------------- multi-block exclusive scan over concatenated counts ----------------
#define SCAN_TPB 256
#define SCAN_EPT 8
#define SCAN_EPB (SCAN_TPB * SCAN_EPT)  // 2048

__global__ void scan_block_sum(const int* __restrict__ cnt, int* __restrict__ bsum, int n) {
    int base = blockIdx.x * SCAN_EPB;
    int t = threadIdx.x;
    int sum = 0;
    for (int i = t; i < SCAN_EPB; i += SCAN_TPB) {
        int idx = base + i;
        if (idx < n) sum += cnt[idx];
    }
    __shared__ int s[SCAN_TPB];
    s[t] = sum;
    __syncthreads();
    for (int ofs = SCAN_TPB / 2; ofs > 0; ofs >>= 1) {
        if (t < ofs) s[t] += s[t + ofs];
        __syncthreads();
    }
    if (t == 0) bsum[blockIdx.x] = s[0];
}

__global__ __launch_bounds__(1024) void scan_bsum_kernel(int* bsum, int nb) {
    __shared__ int s[1024];
    int t = threadIdx.x;
    s[t] = (t < nb) ? bsum[t] : 0;
    __syncthreads();
    for (int ofs = 1; ofs < 1024; ofs <<= 1) {
        int v = (t >= ofs) ? s[t - ofs] : 0;
        __syncthreads();
        s[t] += v;
        __syncthreads();
    }
    if (t < nb) bsum[t] = (t == 0) ? 0 : s[t - 1];
}

__global__ void scan_write_kernel(const int* __restrict__ cnt, const int* __restrict__ bsum,
                                  int* __restrict__ off, int n) {
    int base = blockIdx.x * SCAN_EPB;
    int t = threadIdx.x;
    int lo = base + t * SCAN_EPT;
    int vals[SCAN_EPT];
    int sum = 0;
#pragma unroll
    for (int i = 0; i < SCAN_EPT; ++i) {
        int idx = lo + i;
        vals[i] = (idx < n) ? cnt[idx] : 0;
        sum += vals[i];
    }
    __shared__ int s[SCAN_TPB];
    s[t] = sum;
    __syncthreads();
    for (int ofs = 1; ofs < SCAN_TPB; ofs <<= 1) {
        int v = (t >= ofs) ? s[t - ofs] : 0;
        __syncthreads();
        s[t] += v;
        __syncthreads();
    }
    int run = bsum[blockIdx.x] + ((t == 0) ? 0 : s[t - 1]);
#pragma unroll
    for (int i = 0; i < SCAN_EPT; ++i) {
        int idx = lo + i;
        if (idx < n) off[idx] = run;
        run += vals[i];
        if (idx == n - 1) off[n] = run;
    }
}

// ---- phase B2: place from binned pairs (partition-local scattered writes) ---------
__global__ void placeB_kernel(const int2* __restrict__ pairs, int cap,
                              const int* __restrict__ gcur,
                              const int* o0, const int* o1, const int* o2, const int* o3,
                              int* u0, int* u1, int* u2, int* u3,
                              int* __restrict__ ssorted) {
    int e = blockIdx.y;
    const int* off = (e == 0) ? o0 : (e == 1) ? o1 : (e == 2) ? o2 : o3;
    int* cur       = (e == 0) ? u0 : (e == 1) ? u1 : (e == 2) ? u2 : u3;
    int p = blockIdx.x % NPART;
    int chunk = blockIdx.x / NPART;
    int nchunk = gridDim.x / NPART;
    int len = gcur[e * NPART + p];
    const int2* seg = pairs + ((size_t)e * NPART + p) * cap;
    int per = (len + nchunk - 1) / nchunk;
    int lo = chunk * per, hi = min(lo + per, len);
    for (int i = lo + threadIdx.x; i < hi; i += blockDim.x) {
        int2 pr = seg[i];
        int pos = atomicAdd(&cur[pr.x], 1);
        ssorted[off[pr.x] + pos] = pr.y;
    }
}

// ---- gather-mean: agg[d] = mean h[s], 16 lanes/node, 16-wide index batches --------
__global__ void gather_agg_kernel(const float* __restrict__ hsrc, const int* __restrict__ off,
                                  const int* __restrict__ ssorted,
                                  float* __restrict__ agg, int N) {
    int t = blockIdx.x * blockDim.x + threadIdx.x;
    int d = t >> 4, q = t & 15;
    if (d >= N) return;
    int lo = off[d], hi = off[d + 1];
    float ax = 0, ay = 0, az = 0, aw = 0;
    int gb = (threadIdx.x & 63) & 48;  // group base lane within wave
    for (int j0 = lo; j0 < hi; j0 += 16) {
        int jm = j0 + q;
        int sm = ssorted[(jm < hi) ? jm : (hi - 1)];
        int nb = min(16, hi - j0);
        for (int k = 0; k < nb; ++k) {
            int s = __shfl(sm, gb + k, 64);
            const float4 v = *reinterpret_cast<const float4*>(hsrc + (size_t)s * HD + q * 4);
            ax += v.x; ay += v.y; az += v.z; aw += v.w;
        }
    }
    float r = 1.0f / fmaxf((float)(hi - lo), 1.0f);
    float4 o; o.x = ax * r; o.y = ay * r; o.z = az * r; o.w = aw * r;
    *reinterpret_cast<float4*>(agg + (size_t)d * HD + q * 4) = o;
}

// ---- SAGE out (+ optional fused residual+LN+ELU). Each wave owns a full row. ------
// MODE 0: hn[r,c]  = v                        (gene pass e=1)
// MODE 1: hout[r,c] = elu(LN(hdst + v))       (patient e=0, group e=2; hout==hdst ok)
// MODE 2: v += hn[r,c]; hout = elu(LN(hdst+v)) (gene e=3, consumes e=1's hn)
#define SO_ROWS 64
template<int MODE>
__global__ void sage_kernel(const float* __restrict__ agg, const float* __restrict__ hdst,
                            const float* __restrict__ Wl, const float* __restrict__ bl,
                            const float* __restrict__ Wr,
                            float* __restrict__ hn, float* __restrict__ hout,
                            const float* __restrict__ lng, const float* __restrict__ lnb,
                            int N) {
    __shared__ float sWl[HD * HD];
    __shared__ float sWr[HD * HD];
    int t = threadIdx.x;
    for (int i = t; i < HD * HD; i += 256) { sWl[i] = Wl[i]; sWr[i] = Wr[i]; }
    __syncthreads();
    int c = t & 63;
    int rbase = blockIdx.x * SO_ROWS + (t >> 6);
    float blc = bl[c];
    float gc = 0.0f, bc = 0.0f;
    if (MODE != 0) { gc = lng[c]; bc = lnb[c]; }
    for (int rr = 0; rr < SO_ROWS; rr += 4) {
        int r = rbase + rr;
        if (r >= N) break;
        const float* ar = agg + (size_t)r * HD;
        const float* hr = hdst + (size_t)r * HD;
        float acca = 0.0f, acch = 0.0f;
#pragma unroll 8
        for (int k = 0; k < HD; ++k) {
            acca = fmaf(ar[k], sWl[k * HD + c], acca);
            acch = fmaf(hr[k], sWr[k * HD + c], acch);
        }
        float v = acca + blc + acch;
        if (MODE == 0) {
            hn[(size_t)r * HD + c] = v;
        } else {
            if (MODE == 2) v += hn[(size_t)r * HD + c];
            float x = hr[c] + v;
            float s = x;
#pragma unroll
            for (int o = 32; o > 0; o >>= 1) s += __shfl_xor(s, o, 64);
            float mean = s * (1.0f / 64.0f);
            float dd = x - mean;
            float sq = dd * dd;
#pragma unroll
            for (int o = 32; o > 0; o >>= 1) sq += __shfl_xor(sq, o, 64);
            float var = sq * (1.0f / 64.0f);
            float y = dd * rsqrtf(var + 1e-5f) * gc + bc;
            hout[(size_t)r * HD + c] = elu_f(y);
        }
    }
}

// ---------------- cox head: out = elu(h @ W1 + b1) @ W2 + b2 ----------------
__global__ void cox_kernel(const float* __restrict__ hp,
                           const float* __restrict__ W1, const float* __restrict__ b1,
                           const float* __restrict__ W2, const float* __restrict__ b2,
                           float* __restrict__ out, int N) {
    __shared__ float sW1[HD * 32];
    __shared__ float sW2[32];
    int t = threadIdx.x;
    for (int i = t; i < HD * 32; i += 256) sW1[i] = W1[i];
    if (t < 32) sW2[t] = W2[t];
    __syncthreads();
    int r = blockIdx.x * 8 + (t >> 5);
    int c = t & 31;
    if (r >= N) return;
    const float* hr = hp + (size_t)r * HD;
    float acc = b1[c];
#pragma unroll 8
    for (int k = 0; k < HD; ++k) acc = fmaf(hr[k], sW1[k * 32 + c], acc);
    float z = elu_f(acc) * sW2[c];
#pragma unroll
    for (int o = 16; o > 0; o >>= 1) z += __shfl_xor(z, o, 32);
    if (c == 0) out[r] = z + b2[0];
}

extern "C" void kernel_launch(void* const* d_in, const int* in_sizes, int n_in,
                              void* d_out, int out_size, void* d_ws, size_t ws_size,
                              hipStream_t stream) {
    const float* x_gene    = (const float*)d_in[0];
    const float* x_patient = (const float*)d_in[1];
    const float* x_group   = (const float*)d_in[2];
    const int* srcs[4] = {(const int*)d_in[3], (const int*)d_in[5], (const int*)d_in[7], (const int*)d_in[9]};
    const int* dsts[4] = {(const int*)d_in[4], (const int*)d_in[6], (const int*)d_in[8], (const int*)d_in[10]};
    const float* enc_gene_W    = (const float*)d_in[11];
    const float* enc_gene_b    = (const float*)d_in[12];
    const float* enc_patient_W = (const float*)d_in[13];
    const float* enc_patient_b = (const float*)d_in[14];
    const float* enc_group_W   = (const float*)d_in[15];
    const float* enc_group_b   = (const float*)d_in[16];
    const float* convW_l = (const float*)d_in[17];  // [2,4,64,64]
    const float* convb_l = (const float*)d_in[18];  // [2,4,64]
    const float* convW_r = (const float*)d_in[19];  // [2,4,64,64]
    const float* ln_gamma = (const float*)d_in[20]; // [2,3,64]
    const float* ln_beta  = (const float*)d_in[21];
    const float* coxW1 = (const float*)d_in[22];
    const float* coxb1 = (const float*)d_in[23];
    const float* coxW2 = (const float*)d_in[24];
    const float* coxb2 = (const float*)d_in[25];
    float* out = (float*)d_out;

    const int n_gene    = in_sizes[0] / 11;
    const int n_patient = in_sizes[1] / 3;
    const int n_group   = in_sizes[2] / 4;
    const int E         = in_sizes[3];

    // ---- workspace layout ----
    float* wf = (float*)d_ws;
    float* h_gene  = wf;  wf += (size_t)n_gene * HD;
    float* h_pat   = wf;  wf += (size_t)n_patient * HD;
    float* h_grp   = wf;  wf += (size_t)n_group * HD;
    float* hn_gene = wf;  wf += (size_t)n_gene * HD;
    float* agg_base = wf;                            // 4 agg buffers, contiguous
    float* agg0 = wf;  wf += (size_t)n_patient * HD; // dst=patient
    float* agg1 = wf;  wf += (size_t)n_gene * HD;    // dst=gene
    float* agg2 = wf;  wf += (size_t)n_group * HD;   // dst=group
    float* agg3 = wf;  wf += (size_t)n_gene * HD;    // dst=gene

    int* wi = (int*)wf;
    int* cnt_base = wi;
    int* cnt[4];
    cnt[0] = wi; wi += n_patient;
    cnt[1] = wi; wi += n_gene;
    cnt[2] = wi; wi += n_group;
    cnt[3] = wi; wi += n_gene;
    int* off_base = wi;
    int* off[4];
    off[0] = wi; wi += n_patient;
    off[1] = wi; wi += n_gene;
    off[2] = wi; wi += n_group;
    off[3] = wi; wi += n_gene;
    wi += 1;                                         // sentinel
    int* ssorted = wi;  wi += (size_t)E * 4;
    int* bsum = wi;     wi += 256;
    int* gcur = wi;     wi += 32;

    // pairs buffer ALIASES the agg region (dead before first gather writes agg)
    const int cap = E / NPART + 16384;               // 49 sigma slack; 256*cap*4B <= agg bytes
    int2* pairs = (int2*)agg_base;

    const int deg_total = n_patient + n_gene + n_group + n_gene;

    const float* e_hsrc[4] = {h_gene, h_pat, h_gene, h_grp};
    float*       e_agg[4]  = {agg0, agg1, agg2, agg3};
    const int    e_nd[4]   = {n_patient, n_gene, n_group, n_gene};

    // ---- encoders ----
    encode_kernel<11><<<(n_gene + 3) / 4, 256, 0, stream>>>(x_gene, enc_gene_W, enc_gene_b, h_gene, n_gene);
    encode_kernel<3><<<(n_patient + 3) / 4, 256, 0, stream>>>(x_patient, enc_patient_W, enc_patient_b, h_pat, n_patient);
    encode_kernel<4><<<(n_group + 3) / 4, 256, 0, stream>>>(x_group, enc_group_W, enc_group_b, h_grp, n_group);

    // ---- CSR build: bin -> count -> scan -> place ----
    hipMemsetAsync(gcur, 0, 32 * sizeof(int), stream);
    hipMemsetAsync(cnt_base, 0, (size_t)deg_total * sizeof(int), stream);
    {
        dim3 g(256, 4);
        bin_kernel<<<g, 256, 0, stream>>>(srcs[0], srcs[1], srcs[2], srcs[3],
                                          dsts[0], dsts[1], dsts[2], dsts[3],
                                          e_nd[0], e_nd[1], e_nd[2], e_nd[3],
                                          pairs, cap, gcur, E);
    }
    {
        size_t hist_bytes = (size_t)((n_patient + NPART - 1) / NPART) * sizeof(int);  // max range
        dim3 g(64, 4);
        countB_kernel<<<g, 256, hist_bytes, stream>>>(pairs, cap, gcur,
                                                      cnt[0], cnt[1], cnt[2], cnt[3],
                                                      e_nd[0], e_nd[1], e_nd[2], e_nd[3]);
    }
    {
        int nb = (deg_total + SCAN_EPB - 1) / SCAN_EPB;
        scan_block_sum<<<nb, SCAN_TPB, 0, stream>>>(cnt_base, bsum, deg_total);
        scan_bsum_kernel<<<1, 1024, 0, stream>>>(bsum, nb);
        scan_write_kernel<<<nb, SCAN_TPB, 0, stream>>>(cnt_base, bsum, off_base, deg_total);
    }
    hipMemsetAsync(cnt_base, 0, (size_t)deg_total * sizeof(int), stream);  // reuse as cursors
    {
        dim3 g(256, 4);
        placeB_kernel<<<g, 256, 0, stream>>>(pairs, cap, gcur,
                                             off[0], off[1], off[2], off[3],
                                             cnt[0], cnt[1], cnt[2], cnt[3],
                                             ssorted);
    }

    // ---- 2 GNN layers: all gathers (read old h), then all sage+fused-LN ----
    for (int layer = 0; layer < 2; ++layer) {
        for (int e = 0; e < 4; ++e) {
            gather_agg_kernel<<<((size_t)e_nd[e] * 16 + 255) / 256, 256, 0, stream>>>(
                e_hsrc[e], off[e], ssorted, e_agg[e], e_nd[e]);
        }
        const size_t W = (size_t)HD * HD;
        const float* Wl = convW_l + (size_t)layer * 4 * W;
        const float* bl = convb_l + (size_t)layer * 4 * HD;
        const float* Wr = convW_r + (size_t)layer * 4 * W;
        const float* lg = ln_gamma + (size_t)layer * 3 * HD;
        const float* lb = ln_beta  + (size_t)layer * 3 * HD;
        // e=0: patient, fused LN (ni=1), in-place h_pat
        sage_kernel<1><<<(n_patient + SO_ROWS - 1) / SO_ROWS, 256, 0, stream>>>(
            agg0, h_pat, Wl + 0 * W, bl + 0 * HD, Wr + 0 * W,
            nullptr, h_pat, lg + 1 * HD, lb + 1 * HD, n_patient);
        // e=1: gene, store hn_gene
        sage_kernel<0><<<(n_gene + SO_ROWS - 1) / SO_ROWS, 256, 0, stream>>>(
            agg1, h_gene, Wl + 1 * W, bl + 1 * HD, Wr + 1 * W,
            hn_gene, nullptr, nullptr, nullptr, n_gene);
        // e=2: group, fused LN (ni=2), in-place h_grp
        sage_kernel<1><<<(n_group + SO_ROWS - 1) / SO_ROWS, 256, 0, stream>>>(
            agg2, h_grp, Wl + 2 * W, bl + 2 * HD, Wr + 2 * W,
            nullptr, h_grp, lg + 2 * HD, lb + 2 * HD, n_group);
        // e=3: gene, add hn_gene, fused LN (ni=0), in-place h_gene
        sage_kernel<2><<<(n_gene + SO_ROWS - 1) / SO_ROWS, 256, 0, stream>>>(
            agg3, h_gene, Wl + 3 * W, bl + 3 * HD, Wr + 3 * W,
            hn_gene, h_gene, lg + 0 * HD, lb + 0 * HD, n_gene);
    }

    // ---- cox head ----
    cox_kernel<<<(n_patient + 7) / 8, 256, 0, stream>>>(h_pat, coxW1, coxb1, coxW2, coxb2, out, n_patient);
}